// Round 10
// baseline (267.573 us; speedup 1.0000x reference)
//
#include <hip/hip_runtime.h>
#include <hip/hip_bf16.h>
#include <stdint.h>

typedef float f4    __attribute__((ext_vector_type(4)));
typedef float f32x4 __attribute__((ext_vector_type(4)));
typedef short s16x8 __attribute__((ext_vector_type(8)));
typedef short s16x4 __attribute__((ext_vector_type(4)));
typedef unsigned short u16;

#define T_LEN 4096
#define NHEAD 16
#define DHEAD 64
#define KVBLK 64
#define NT    (T_LEN / KVBLK)

#if __has_builtin(__builtin_amdgcn_exp2f)
#define EXP2(x) __builtin_amdgcn_exp2f(x)
#else
#define EXP2(x) exp2f(x)
#endif

// partial slot: 64 rows x 64 d acc + 64 lsum = 4160 floats
#define SLOT_F 4160
#define CONV_BYTES (16u * 4096u * 64u * 2u * 2u)     // Kb + VT bf16 = 16.78 MB
// slots(NCB) = 704 + 256*NCB  (h8,h9:128 each; h10:192; h11:256; h12-15: 64*NCB each)
#define CHUNK_BYTES(NCB) ((size_t)CONV_BYTES + (size_t)(704 + 256*(NCB)) * SLOT_F * 4u)

__device__ __forceinline__ uint32_t pk2(float a, float b){
  uint32_t ua = __builtin_bit_cast(uint32_t, a) + 0x8000u;
  uint32_t ub = __builtin_bit_cast(uint32_t, b) + 0x8000u;
  return __builtin_amdgcn_perm(ub, ua, 0x07060302u);
}
__device__ __forceinline__ int swk(int r){ return (r ^ (r >> 3)) & 7; }
__device__ __forceinline__ int sw(int r){ return swk(r) << 3; }
__device__ __forceinline__ int slotbase(int h, int ncb){
  return (h <= 9) ? (h - 8) * 128 : (h == 10 ? 256 : (h == 11 ? 448 : 704 + (h - 12) * 64 * ncb));
}

// ---------------- fused pre-pass: K -> bf16 ; V -> bf16 V^T ----------------
__global__ __launch_bounds__(256)
void cvt_kv(const float* __restrict__ K, const float* __restrict__ V,
            u16* __restrict__ Kb, u16* __restrict__ VT){
  __shared__ u16 tile[64][66];
  if (blockIdx.x < 2048){
    const size_t i = ((size_t)blockIdx.x * 256 + threadIdx.x) * 8;
    f4 a = *(const f4*)(K + i);
    f4 b = *(const f4*)(K + i + 4);
    union { uint32_t w[4]; s16x8 v; } u;
    u.w[0] = pk2(a[0], a[1]); u.w[1] = pk2(a[2], a[3]);
    u.w[2] = pk2(b[0], b[1]); u.w[3] = pk2(b[2], b[3]);
    *(s16x8*)(Kb + i) = u.v;
  } else {
    const int vb = blockIdx.x - 2048;
    const int h  = vb >> 6;
    const int kt = vb & 63;
    const int t  = threadIdx.x;
    const float* Vh = V + ((size_t)h * T_LEN + kt * 64) * DHEAD;

    const int r = t >> 2, c = (t & 3) * 16;
    f4 x0 = *(const f4*)(Vh + r*64 + c);
    f4 x1 = *(const f4*)(Vh + r*64 + c + 4);
    f4 x2 = *(const f4*)(Vh + r*64 + c + 8);
    f4 x3 = *(const f4*)(Vh + r*64 + c + 12);
    uint32_t* tp = (uint32_t*)&tile[r][c];
    tp[0] = pk2(x0[0],x0[1]); tp[1] = pk2(x0[2],x0[3]);
    tp[2] = pk2(x1[0],x1[1]); tp[3] = pk2(x1[2],x1[3]);
    tp[4] = pk2(x2[0],x2[1]); tp[5] = pk2(x2[2],x2[3]);
    tp[6] = pk2(x3[0],x3[1]); tp[7] = pk2(x3[2],x3[3]);
    __syncthreads();

    const int d = t >> 2, ks = (t & 3) * 16;
    u16* op = VT + ((size_t)h * DHEAD + d) * T_LEN + kt * 64 + ks;
    union { uint32_t w[4]; s16x8 v; } o0, o1;
#pragma unroll
    for (int q = 0; q < 4; ++q)
      o0.w[q] = (uint32_t)tile[ks + 2*q][d]     | ((uint32_t)tile[ks + 2*q + 1][d] << 16);
#pragma unroll
    for (int q = 0; q < 4; ++q)
      o1.w[q] = (uint32_t)tile[ks + 8 + 2*q][d] | ((uint32_t)tile[ks + 9 + 2*q][d] << 16);
    *(s16x8*)(op)     = o0.v;
    *(s16x8*)(op + 8) = o1.v;
  }
}

// ---------------- chunked attention (windowed + KV-split, partial combine) ----------------
template<int NCB>
__global__ __launch_bounds__(256, 5)
void alibi_attn5(const float* __restrict__ Qg,
                 const u16* __restrict__ Kb,
                 const u16* __restrict__ VTb,
                 float* __restrict__ Og,
                 float* __restrict__ part)
{
  __shared__ u16 kbuf[2][KVBLK * DHEAD];
  __shared__ u16 vbuf[2][DHEAD * KVBLK];

  // bid -> (h, qt, chunk c of n). Heavy heads first (better packing).
  const int bid = blockIdx.x;
  constexpr int B12 = 256 * NCB;
  int h, qt, c, n;
  if (bid < B12){                       // h 12..15, NC=NCB
    h = 12 + bid / (64 * NCB); int r = bid % (64 * NCB); qt = r / NCB; c = r % NCB; n = NCB;
  } else if (bid < B12 + 256){          // h 11, NC=4
    int r = bid - B12; h = 11; qt = r >> 2; c = r & 3; n = 4;
  } else if (bid < B12 + 448){          // h 10, NC=3
    int r = bid - B12 - 256; h = 10; qt = r / 3; c = r - qt * 3; n = 3;
  } else if (bid < B12 + 704){          // h 8..9, NC=2
    int r = bid - B12 - 448; h = 8 + (r >> 7); r &= 127; qt = r >> 1; c = r & 1; n = 2;
  } else {                              // h 0..7, NC=1
    int r = bid - B12 - 704; h = r >> 6; qt = r & 63; c = 0; n = 1;
  }

  const int tid  = threadIdx.x;
  const int wv   = tid >> 6;
  const int lane = tid & 63;
  const int lg   = lane >> 4;
  const int ln   = lane & 15;

  const int q0   = qt * 64;
  const int qrow = q0 + wv * 16 + ln;
  const float slope = exp2f(-0.5f * (float)(h + 1));
  const float cs = 0.125f * 1.44269504089f;
  const float bs = slope * 1.44269504089f;
  const size_t headoff = (size_t)h * T_LEN * DHEAD;

  // ALiBi window (keys with bs*dist > 36 are negligible), then chunk c of n
  const int Di = (int)(36.0f / bs);
  int lo = (q0 - Di) >> 6;           if (lo < 0) lo = 0;
  int hi = (q0 + 63 + Di) >> 6;      if (hi > NT - 1) hi = NT - 1;
  const int len = hi - lo + 1;
  const int start = lo + (c * len) / n;
  const int end   = lo + ((c + 1) * len) / n;   // exclusive

  // ---- Q fragments ----
  s16x8 qf0, qf1;
  {
    const float* qp = Qg + headoff + (size_t)qrow * DHEAD + lg * 8;
    f4 x = *(const f4*)qp;        f4 y = *(const f4*)(qp + 4);
    f4 z = *(const f4*)(qp + 32); f4 v = *(const f4*)(qp + 36);
    union { uint32_t w_[4]; s16x8 v_; } u0, u1;
    u0.w_[0] = pk2(x[0]*cs, x[1]*cs); u0.w_[1] = pk2(x[2]*cs, x[3]*cs);
    u0.w_[2] = pk2(y[0]*cs, y[1]*cs); u0.w_[3] = pk2(y[2]*cs, y[3]*cs);
    u1.w_[0] = pk2(z[0]*cs, z[1]*cs); u1.w_[1] = pk2(z[2]*cs, z[3]*cs);
    u1.w_[2] = pk2(v[0]*cs, v[1]*cs); u1.w_[3] = pk2(v[2]*cs, v[3]*cs);
    qf0 = u0.v_; qf1 = u1.v_;
  }

  f32x4 acc[4];
#pragma unroll
  for (int dt = 0; dt < 4; ++dt) acc[dt] = (f32x4)(0.0f);
  float lsum = 0.0f;
  const float base0 = (float)qrow - (float)(lg * 4);

  // ---- hoisted swizzled LDS read byte-offsets ----
  int koffs[4][2];
#pragma unroll
  for (int kt = 0; kt < 4; ++kt){
    const int key = kt*16 + ln, sz = sw(key);
    koffs[kt][0] = (((key*64      + lg*8) ^ sz)) * 2;
    koffs[kt][1] = (((key*64 + 32 + lg*8) ^ sz)) * 2;
  }
  int voffs[4][4];
#pragma unroll
  for (int dt = 0; dt < 4; ++dt){
    const int d = dt*16 + ln, sz = sw(d);
#pragma unroll
    for (int kt = 0; kt < 4; ++kt)
      voffs[dt][kt] = (((d*64 + kt*16 + lg*4) ^ sz)) * 2;
  }

  // ---- staging: linear LDS dest, inverse-swizzled global source ----
  const u16* Kh = Kb  + headoff;
  const u16* Vh = VTb + headoff;
  const int sA = wv * 128 + lane;
  const int sB = sA + 64;
  const int keyA = sA >> 3, gA = (sA & 7) ^ swk(keyA);
  const int keyB = sB >> 3, gB = (sB & 7) ^ swk(keyB);
  const int kidxA = keyA * 64 + gA * 8;
  const int kidxB = keyB * 64 + gB * 8;
  const int vidxA = keyA * T_LEN + gA * 8;
  const int vidxB = keyB * T_LEN + gB * 8;
  const int dstA = sA * 16, dstB = sB * 16;

  s16x8 rkA, rkB, rvA, rvB;
  auto ldregs = [&](int t){
    const u16* kp = Kh + (size_t)t * (KVBLK * DHEAD);
    const u16* vp = Vh + (size_t)t * KVBLK;
    rkA = *(const s16x8*)(kp + kidxA);  rkB = *(const s16x8*)(kp + kidxB);
    rvA = *(const s16x8*)(vp + vidxA);  rvB = *(const s16x8*)(vp + vidxB);
  };
  auto wrregs = [&](u16* kb_, u16* vb_){
    *(s16x8*)((char*)kb_ + dstA) = rkA;  *(s16x8*)((char*)kb_ + dstB) = rkB;
    *(s16x8*)((char*)vb_ + dstA) = rvA;  *(s16x8*)((char*)vb_ + dstB) = rvB;
  };

  auto compute = [&](const u16* kb_, const u16* vb_, int kv){
    f32x4 S[4];
    __builtin_amdgcn_s_setprio(1);
#pragma unroll
    for (int kt = 0; kt < 4; ++kt){
      s16x8 k0 = *(const s16x8*)((const char*)kb_ + koffs[kt][0]);
      s16x8 k1 = *(const s16x8*)((const char*)kb_ + koffs[kt][1]);
      f32x4 cc = (f32x4)(0.0f);
      cc = __builtin_amdgcn_mfma_f32_16x16x32_bf16(k0, qf0, cc, 0, 0, 0);
      cc = __builtin_amdgcn_mfma_f32_16x16x32_bf16(k1, qf1, cc, 0, 0, 0);
      S[kt] = cc;
    }
    __builtin_amdgcn_s_setprio(0);

    const float bi = base0 - (float)(kv * KVBLK);
    float p[16];
#pragma unroll
    for (int kt = 0; kt < 4; ++kt)
#pragma unroll
      for (int r = 0; r < 4; ++r)
        p[kt*4 + r] = EXP2(fmaf(-bs, fabsf(bi - (float)(kt*16 + r)), S[kt][r]));

    lsum += (((p[0]+p[1]) + (p[2]+p[3])) + ((p[4]+p[5]) + (p[6]+p[7])))
          + (((p[8]+p[9]) + (p[10]+p[11])) + ((p[12]+p[13]) + (p[14]+p[15])));

    s16x4 pb[4];
#pragma unroll
    for (int kt = 0; kt < 4; ++kt){
      union { uint32_t w_[2]; s16x4 v_; } u;
      u.w_[0] = pk2(p[kt*4+0], p[kt*4+1]);
      u.w_[1] = pk2(p[kt*4+2], p[kt*4+3]);
      pb[kt] = u.v_;
    }

    __builtin_amdgcn_s_setprio(1);
#pragma unroll
    for (int dt = 0; dt < 4; ++dt){
#pragma unroll
      for (int kt = 0; kt < 4; ++kt){
        const s16x4 vf = *(const s16x4*)((const char*)vb_ + voffs[dt][kt]);
        acc[dt] = __builtin_amdgcn_mfma_f32_16x16x16bf16_1k(vf, pb[kt], acc[dt], 0, 0, 0);
      }
    }
    __builtin_amdgcn_s_setprio(0);
  };

  if (start < end){
    ldregs(start);
    wrregs(kbuf[0], vbuf[0]);
    __syncthreads();

    const int hi_i = end - 1;
    int t = start;
#pragma unroll 1
    while (t + 1 < hi_i){
      ldregs(t + 1);
      compute(kbuf[0], vbuf[0], t);
      wrregs(kbuf[1], vbuf[1]);
      __syncthreads();
      ldregs(t + 2);
      compute(kbuf[1], vbuf[1], t + 1);
      wrregs(kbuf[0], vbuf[0]);
      __syncthreads();
      t += 2;
    }
    if (t < hi_i){
      ldregs(t + 1);
      compute(kbuf[0], vbuf[0], t);
      wrregs(kbuf[1], vbuf[1]);
      __syncthreads();
      compute(kbuf[1], vbuf[1], t + 1);
    } else {
      compute(kbuf[0], vbuf[0], t);
    }
  }

  // ---- row lsum reduce ----
  lsum += __shfl_xor(lsum, 16, 64);
  lsum += __shfl_xor(lsum, 32, 64);

  if (n == 1){
    const float inv = 1.0f / lsum;
    float* op = Og + headoff + (size_t)qrow * DHEAD + lg * 4;
#pragma unroll
    for (int dt = 0; dt < 4; ++dt){
      f4 o;
      o[0] = acc[dt][0] * inv; o[1] = acc[dt][1] * inv;
      o[2] = acc[dt][2] * inv; o[3] = acc[dt][3] * inv;
      *(f4*)(op + dt*16) = o;
    }
  } else {
    float* slot = part + (size_t)(slotbase(h, NCB) + qt * n + c) * SLOT_F;
    const int row = wv * 16 + ln;
    float* op = slot + row * 64 + lg * 4;
#pragma unroll
    for (int dt = 0; dt < 4; ++dt)
      *(f4*)(op + dt*16) = acc[dt];
    if (lg == 0) slot[4096 + row] = lsum;
  }
}

// ---------------- combine partials for h 8..15 ----------------
template<int NCB>
__global__ __launch_bounds__(256)
void combine_k(const float* __restrict__ part, float* __restrict__ Og){
  const int h  = 8 + (blockIdx.x >> 6);
  const int qt = blockIdx.x & 63;
  const int n  = (h <= 9) ? 2 : (h == 10 ? 3 : (h == 11 ? 4 : NCB));
  const int sb = slotbase(h, NCB) + qt * n;

  const int t   = threadIdx.x;
  const int row = t >> 2;
  const int seg = (t & 3) * 16;

  f4 a0 = (f4)(0.0f), a1 = (f4)(0.0f), a2 = (f4)(0.0f), a3 = (f4)(0.0f);
  float l = 0.0f;
#pragma unroll 1
  for (int c = 0; c < n; ++c){
    const float* sp = part + (size_t)(sb + c) * SLOT_F;
    const float* rp = sp + row * 64 + seg;
    a0 += *(const f4*)(rp);
    a1 += *(const f4*)(rp + 4);
    a2 += *(const f4*)(rp + 8);
    a3 += *(const f4*)(rp + 12);
    l  += sp[4096 + row];
  }
  const float inv = 1.0f / l;
  float* op = Og + (((size_t)h * T_LEN + qt * 64 + row) * DHEAD) + seg;
  f4 o0, o1, o2, o3;
  o0[0]=a0[0]*inv; o0[1]=a0[1]*inv; o0[2]=a0[2]*inv; o0[3]=a0[3]*inv;
  o1[0]=a1[0]*inv; o1[1]=a1[1]*inv; o1[2]=a1[2]*inv; o1[3]=a1[3]*inv;
  o2[0]=a2[0]*inv; o2[1]=a2[1]*inv; o2[2]=a2[2]*inv; o2[3]=a2[3]*inv;
  o3[0]=a3[0]*inv; o3[1]=a3[1]*inv; o3[2]=a3[2]*inv; o3[3]=a3[3]*inv;
  *(f4*)(op)      = o0;
  *(f4*)(op + 4)  = o1;
  *(f4*)(op + 8)  = o2;
  *(f4*)(op + 12) = o3;
}

// ---------------- windowed, unsplit kernel (ws >= 16.8MB fallback) ----------------
__global__ __launch_bounds__(256, 4)
void alibi_attn4(const float* __restrict__ Qg,
                 const u16* __restrict__ Kb,
                 const u16* __restrict__ VTb,
                 float* __restrict__ Og)
{
  __shared__ u16 kbuf[2][KVBLK * DHEAD];
  __shared__ u16 vbuf[2][DHEAD * KVBLK];

  const int bid = blockIdx.x;
  const int fid = (bid & 7) * 128 + (bid >> 3);
  const int h  = fid & 15;
  const int qt = fid >> 4;

  const int tid  = threadIdx.x;
  const int wv   = tid >> 6;
  const int lane = tid & 63;
  const int lg   = lane >> 4;
  const int ln   = lane & 15;

  const int q0   = qt * 64;
  const int qrow = q0 + wv * 16 + ln;
  const float slope = exp2f(-0.5f * (float)(h + 1));
  const float cs = 0.125f * 1.44269504089f;
  const float bs = slope * 1.44269504089f;
  const size_t headoff = (size_t)h * T_LEN * DHEAD;

  const int Di = (int)(36.0f / bs);
  int lo = (q0 - Di) >> 6;           if (lo < 0) lo = 0;
  int hi = (q0 + 63 + Di) >> 6;      if (hi > NT - 1) hi = NT - 1;

  s16x8 qf0, qf1;
  {
    const float* qp = Qg + headoff + (size_t)qrow * DHEAD + lg * 8;
    f4 x = *(const f4*)qp;        f4 y = *(const f4*)(qp + 4);
    f4 z = *(const f4*)(qp + 32); f4 v = *(const f4*)(qp + 36);
    union { uint32_t w_[4]; s16x8 v_; } u0, u1;
    u0.w_[0] = pk2(x[0]*cs, x[1]*cs); u0.w_[1] = pk2(x[2]*cs, x[3]*cs);
    u0.w_[2] = pk2(y[0]*cs, y[1]*cs); u0.w_[3] = pk2(y[2]*cs, y[3]*cs);
    u1.w_[0] = pk2(z[0]*cs, z[1]*cs); u1.w_[1] = pk2(z[2]*cs, z[3]*cs);
    u1.w_[2] = pk2(v[0]*cs, v[1]*cs); u1.w_[3] = pk2(v[2]*cs, v[3]*cs);
    qf0 = u0.v_; qf1 = u1.v_;
  }

  f32x4 acc[4];
#pragma unroll
  for (int dt = 0; dt < 4; ++dt) acc[dt] = (f32x4)(0.0f);
  float lsum = 0.0f;
  const float base0 = (float)qrow - (float)(lg * 4);

  int koffs[4][2];
#pragma unroll
  for (int kt = 0; kt < 4; ++kt){
    const int key = kt*16 + ln, sz = sw(key);
    koffs[kt][0] = (((key*64      + lg*8) ^ sz)) * 2;
    koffs[kt][1] = (((key*64 + 32 + lg*8) ^ sz)) * 2;
  }
  int voffs[4][4];
#pragma unroll
  for (int dt = 0; dt < 4; ++dt){
    const int d = dt*16 + ln, sz = sw(d);
#pragma unroll
    for (int kt = 0; kt < 4; ++kt)
      voffs[dt][kt] = (((d*64 + kt*16 + lg*4) ^ sz)) * 2;
  }

  const u16* Kh = Kb  + headoff;
  const u16* Vh = VTb + headoff;
  const int sA = wv * 128 + lane;
  const int sB = sA + 64;
  const int keyA = sA >> 3, gA = (sA & 7) ^ swk(keyA);
  const int keyB = sB >> 3, gB = (sB & 7) ^ swk(keyB);
  const int kidxA = keyA * 64 + gA * 8;
  const int kidxB = keyB * 64 + gB * 8;
  const int vidxA = keyA * T_LEN + gA * 8;
  const int vidxB = keyB * T_LEN + gB * 8;
  const int dstA = sA * 16, dstB = sB * 16;

  s16x8 rkA, rkB, rvA, rvB;
  auto ldregs = [&](int t){
    const u16* kp = Kh + (size_t)t * (KVBLK * DHEAD);
    const u16* vp = Vh + (size_t)t * KVBLK;
    rkA = *(const s16x8*)(kp + kidxA);  rkB = *(const s16x8*)(kp + kidxB);
    rvA = *(const s16x8*)(vp + vidxA);  rvB = *(const s16x8*)(vp + vidxB);
  };
  auto wrregs = [&](u16* kb_, u16* vb_){
    *(s16x8*)((char*)kb_ + dstA) = rkA;  *(s16x8*)((char*)kb_ + dstB) = rkB;
    *(s16x8*)((char*)vb_ + dstA) = rvA;  *(s16x8*)((char*)vb_ + dstB) = rvB;
  };

  auto compute = [&](const u16* kb_, const u16* vb_, int kv){
    f32x4 S[4];
    __builtin_amdgcn_s_setprio(1);
#pragma unroll
    for (int kt = 0; kt < 4; ++kt){
      s16x8 k0 = *(const s16x8*)((const char*)kb_ + koffs[kt][0]);
      s16x8 k1 = *(const s16x8*)((const char*)kb_ + koffs[kt][1]);
      f32x4 cc = (f32x4)(0.0f);
      cc = __builtin_amdgcn_mfma_f32_16x16x32_bf16(k0, qf0, cc, 0, 0, 0);
      cc = __builtin_amdgcn_mfma_f32_16x16x32_bf16(k1, qf1, cc, 0, 0, 0);
      S[kt] = cc;
    }
    __builtin_amdgcn_s_setprio(0);

    const float bi = base0 - (float)(kv * KVBLK);
    float p[16];
#pragma unroll
    for (int kt = 0; kt < 4; ++kt)
#pragma unroll
      for (int r = 0; r < 4; ++r)
        p[kt*4 + r] = EXP2(fmaf(-bs, fabsf(bi - (float)(kt*16 + r)), S[kt][r]));

    lsum += (((p[0]+p[1]) + (p[2]+p[3])) + ((p[4]+p[5]) + (p[6]+p[7])))
          + (((p[8]+p[9]) + (p[10]+p[11])) + ((p[12]+p[13]) + (p[14]+p[15])));

    s16x4 pb[4];
#pragma unroll
    for (int kt = 0; kt < 4; ++kt){
      union { uint32_t w_[2]; s16x4 v_; } u;
      u.w_[0] = pk2(p[kt*4+0], p[kt*4+1]);
      u.w_[1] = pk2(p[kt*4+2], p[kt*4+3]);
      pb[kt] = u.v_;
    }

    __builtin_amdgcn_s_setprio(1);
#pragma unroll
    for (int dt = 0; dt < 4; ++dt){
#pragma unroll
      for (int kt = 0; kt < 4; ++kt){
        const s16x4 vf = *(const s16x4*)((const char*)vb_ + voffs[dt][kt]);
        acc[dt] = __builtin_amdgcn_mfma_f32_16x16x16bf16_1k(vf, pb[kt], acc[dt], 0, 0, 0);
      }
    }
    __builtin_amdgcn_s_setprio(0);
  };

  ldregs(lo);
  wrregs(kbuf[0], vbuf[0]);
  __syncthreads();

  int t = lo;
#pragma unroll 1
  while (t + 1 < hi){
    ldregs(t + 1);
    compute(kbuf[0], vbuf[0], t);
    wrregs(kbuf[1], vbuf[1]);
    __syncthreads();
    ldregs(t + 2);
    compute(kbuf[1], vbuf[1], t + 1);
    wrregs(kbuf[0], vbuf[0]);
    __syncthreads();
    t += 2;
  }
  if (t < hi){
    ldregs(t + 1);
    compute(kbuf[0], vbuf[0], t);
    wrregs(kbuf[1], vbuf[1]);
    __syncthreads();
    compute(kbuf[1], vbuf[1], t + 1);
  } else {
    compute(kbuf[0], vbuf[0], t);
  }

  lsum += __shfl_xor(lsum, 16, 64);
  lsum += __shfl_xor(lsum, 32, 64);
  const float inv = 1.0f / lsum;
  float* op = Og + headoff + (size_t)qrow * DHEAD + lg * 4;
#pragma unroll
  for (int dt = 0; dt < 4; ++dt){
    f4 o;
    o[0] = acc[dt][0] * inv; o[1] = acc[dt][1] * inv;
    o[2] = acc[dt][2] * inv; o[3] = acc[dt][3] * inv;
    *(f4*)(op + dt*16) = o;
  }
}

// ---------------- no-ws fallback (round-5 kernel) ----------------
__global__ __launch_bounds__(256, 2)
void alibi_attn_fb(const float* __restrict__ Qg,
                   const float* __restrict__ Kg,
                   const float* __restrict__ Vg,
                   float* __restrict__ Og)
{
  __shared__ u16 kbuf[2][KVBLK * DHEAD];
  __shared__ u16 vbuf[2][DHEAD * KVBLK];

  const int bid = blockIdx.x;
  const int fid = (bid & 7) * 64 + (bid >> 3);
  const int h  = fid >> 5;
  const int qt = fid & 31;

  const int tid  = threadIdx.x;
  const int wave = tid >> 6;
  const int lane = tid & 63;
  const int lg   = lane >> 4;
  const int ln   = lane & 15;

  const int qb = qt * 128 + wave * 32;
  const float slope = exp2f(-0.5f * (float)(h + 1));
  const float cs = 0.125f * 1.44269504089f;
  const float bs = slope * 1.44269504089f;
  const size_t headoff = (size_t)h * T_LEN * DHEAD;

  s16x8 qf[2][2];
#pragma unroll
  for (int rg = 0; rg < 2; ++rg)
#pragma unroll
    for (int dh = 0; dh < 2; ++dh){
      const float* qp = Qg + headoff + (size_t)(qb + rg*16 + ln) * DHEAD + dh*32 + lg*8;
      f4 x = *(const f4*)qp;
      f4 y = *(const f4*)(qp + 4);
      union { uint32_t w[4]; s16x8 v; } u;
      u.w[0] = pk2(x[0]*cs, x[1]*cs);
      u.w[1] = pk2(x[2]*cs, x[3]*cs);
      u.w[2] = pk2(y[0]*cs, y[1]*cs);
      u.w[3] = pk2(y[2]*cs, y[3]*cs);
      qf[rg][dh] = u.v;
    }

  f32x4 acc[2][4];
#pragma unroll
  for (int rg = 0; rg < 2; ++rg)
#pragma unroll
    for (int dt = 0; dt < 4; ++dt) acc[rg][dt] = (f32x4)(0.0f);
  float mreg[2] = {-1e30f, -1e30f};
  float lreg[2] = {0.0f, 0.0f};
  const float qposf[2] = {(float)(qb + ln), (float)(qb + 16 + ln)};
  const float koffb = (float)(lg * 4);

  f4 st4[8];
  const int vk0  = (tid >> 2) * 2;
  const int vseg = (tid & 3) * 16;
  const int krow = (tid - 128) >> 1;
  const int kseg = ((tid - 128) & 1) * 32;
  const float* Vb = Vg + headoff;
  const float* Kb_ = Kg + headoff;

  auto stage_load = [&](int kv){
    const int kb = kv * KVBLK;
    if (tid < 128){
      const float* vp = Vb + (size_t)(kb + vk0) * DHEAD + vseg;
      st4[0] = *(const f4*)(vp);      st4[1] = *(const f4*)(vp + 4);
      st4[2] = *(const f4*)(vp + 8);  st4[3] = *(const f4*)(vp + 12);
      st4[4] = *(const f4*)(vp + 64); st4[5] = *(const f4*)(vp + 68);
      st4[6] = *(const f4*)(vp + 72); st4[7] = *(const f4*)(vp + 76);
    } else {
      const float* kp = Kb_ + (size_t)(kb + krow) * DHEAD + kseg;
#pragma unroll
      for (int j = 0; j < 8; ++j) st4[j] = *(const f4*)(kp + j*4);
    }
  };
  auto stage_store = [&](int b){
    if (tid < 128){
#pragma unroll
      for (int i = 0; i < 16; ++i){
        const int d = vseg + i;
        uint32_t pr = pk2(st4[i>>2][i&3], st4[4 + (i>>2)][i&3]);
        *(uint32_t*)&vbuf[b][(d*64 + vk0) ^ sw(d)] = pr;
      }
    } else {
#pragma unroll
      for (int i = 0; i < 4; ++i){
        union { uint32_t w[4]; s16x8 v; } u;
        u.w[0] = pk2(st4[i*2][0],   st4[i*2][1]);
        u.w[1] = pk2(st4[i*2][2],   st4[i*2][3]);
        u.w[2] = pk2(st4[i*2+1][0], st4[i*2+1][1]);
        u.w[3] = pk2(st4[i*2+1][2], st4[i*2+1][3]);
        *(s16x8*)&kbuf[b][(krow*64 + kseg + i*8) ^ sw(krow)] = u.v;
      }
    }
  };

  stage_load(0);
  stage_store(0);
  __syncthreads();
  int cur = 0;

#pragma unroll 1
  for (int kv = 0; kv < NT; ++kv){
    if (kv + 1 < NT) stage_load(kv + 1);

    const float kbf = (float)(kv * KVBLK);
    const u16* kb_ = kbuf[cur];
    const u16* vb_ = vbuf[cur];

    s16x8 kf[4][2];
#pragma unroll
    for (int kt = 0; kt < 4; ++kt){
      const int key = kt*16 + ln;
      const int sz  = sw(key);
      kf[kt][0] = *(const s16x8*)&kb_[(key*64 +      lg*8) ^ sz];
      kf[kt][1] = *(const s16x8*)&kb_[(key*64 + 32 + lg*8) ^ sz];
    }
    f32x4 S[2][4];
#pragma unroll
    for (int rg = 0; rg < 2; ++rg)
#pragma unroll
      for (int kt = 0; kt < 4; ++kt){
        f32x4 c = (f32x4)(0.0f);
        c = __builtin_amdgcn_mfma_f32_16x16x32_bf16(kf[kt][0], qf[rg][0], c, 0, 0, 0);
        c = __builtin_amdgcn_mfma_f32_16x16x32_bf16(kf[kt][1], qf[rg][1], c, 0, 0, 0);
        S[rg][kt] = c;
      }

    s16x4 pb[2][4];
#pragma unroll
    for (int rg = 0; rg < 2; ++rg){
      const float base = qposf[rg] - kbf - koffb;
#pragma unroll
      for (int kt = 0; kt < 4; ++kt)
#pragma unroll
        for (int r = 0; r < 4; ++r)
          S[rg][kt][r] = fmaf(-bs, fabsf(base - (float)(kt*16 + r)), S[rg][kt][r]);

      float a0 = fmaxf(fmaxf(S[rg][0][0], S[rg][0][1]), fmaxf(S[rg][0][2], S[rg][0][3]));
      float a1 = fmaxf(fmaxf(S[rg][1][0], S[rg][1][1]), fmaxf(S[rg][1][2], S[rg][1][3]));
      float a2 = fmaxf(fmaxf(S[rg][2][0], S[rg][2][1]), fmaxf(S[rg][2][2], S[rg][2][3]));
      float a3 = fmaxf(fmaxf(S[rg][3][0], S[rg][3][1]), fmaxf(S[rg][3][2], S[rg][3][3]));
      float mx = fmaxf(fmaxf(a0, a1), fmaxf(a2, a3));
      mx = fmaxf(mx, __shfl_xor(mx, 16, 64));
      mx = fmaxf(mx, __shfl_xor(mx, 32, 64));

      const float mo = mreg[rg];
      const float mn = fmaxf(mo, mx);
      const float scl = EXP2(mo - mn);
      mreg[rg] = mn;

      float p[16];
#pragma unroll
      for (int kt = 0; kt < 4; ++kt)
#pragma unroll
        for (int r = 0; r < 4; ++r)
          p[kt*4 + r] = EXP2(S[rg][kt][r] - mn);

      float s0 = (p[0]+p[1]) + (p[2]+p[3]);
      float s1 = (p[4]+p[5]) + (p[6]+p[7]);
      float s2 = (p[8]+p[9]) + (p[10]+p[11]);
      float s3 = (p[12]+p[13]) + (p[14]+p[15]);
      float sum = (s0+s1) + (s2+s3);
      sum += __shfl_xor(sum, 16, 64);
      sum += __shfl_xor(sum, 32, 64);
      lreg[rg] = lreg[rg] * scl + sum;

#pragma unroll
      for (int dt = 0; dt < 4; ++dt) acc[rg][dt] *= scl;

#pragma unroll
      for (int kt = 0; kt < 4; ++kt){
        union { uint32_t w[2]; s16x4 v; } u;
        u.w[0] = pk2(p[kt*4+0], p[kt*4+1]);
        u.w[1] = pk2(p[kt*4+2], p[kt*4+3]);
        pb[rg][kt] = u.v;
      }
    }

#pragma unroll
    for (int dt = 0; dt < 4; ++dt){
      const int d  = dt*16 + ln;
      const int sz = sw(d);
#pragma unroll
      for (int kt = 0; kt < 4; ++kt){
        const s16x4 vf = *(const s16x4*)&vb_[(d*64 + kt*16 + lg*4) ^ sz];
        acc[0][dt] = __builtin_amdgcn_mfma_f32_16x16x16bf16_1k(vf, pb[0][kt], acc[0][dt], 0, 0, 0);
        acc[1][dt] = __builtin_amdgcn_mfma_f32_16x16x16bf16_1k(vf, pb[1][kt], acc[1][dt], 0, 0, 0);
      }
    }

    if (kv + 1 < NT){
      stage_store(cur ^ 1);
      __syncthreads();
      cur ^= 1;
    }
  }

#pragma unroll
  for (int rg = 0; rg < 2; ++rg){
    const float inv = 1.0f / lreg[rg];
    float* op = Og + headoff + (size_t)(qb + rg*16 + ln) * DHEAD + lg*4;
#pragma unroll
    for (int dt = 0; dt < 4; ++dt){
      f4 o;
      o[0] = acc[rg][dt][0] * inv;
      o[1] = acc[rg][dt][1] * inv;
      o[2] = acc[rg][dt][2] * inv;
      o[3] = acc[rg][dt][3] * inv;
      *(f4*)(op + dt*16) = o;
    }
  }
}

extern "C" void kernel_launch(void* const* d_in, const int* in_sizes, int n_in,
                              void* d_out, int out_size, void* d_ws, size_t ws_size,
                              hipStream_t stream)
{
  const float* Q = (const float*)d_in[0];
  const float* K = (const float*)d_in[1];
  const float* V = (const float*)d_in[2];
  float* O = (float*)d_out;

  if (ws_size >= CONV_BYTES){
    u16* Kb = (u16*)d_ws;
    u16* VT = Kb + (size_t)NHEAD * T_LEN * DHEAD;
    hipLaunchKernelGGL(cvt_kv, dim3(3072), dim3(256), 0, stream, K, V, Kb, VT);

    if (ws_size >= CHUNK_BYTES(5)){
      float* part = (float*)((char*)d_ws + CONV_BYTES);
      hipLaunchKernelGGL((alibi_attn5<5>), dim3(1216 + 256*5), dim3(256), 0, stream, Q, Kb, VT, O, part);
      hipLaunchKernelGGL((combine_k<5>), dim3(512), dim3(256), 0, stream, part, O);
    } else if (ws_size >= CHUNK_BYTES(4)){
      float* part = (float*)((char*)d_ws + CONV_BYTES);
      hipLaunchKernelGGL((alibi_attn5<4>), dim3(1216 + 256*4), dim3(256), 0, stream, Q, Kb, VT, O, part);
      hipLaunchKernelGGL((combine_k<4>), dim3(512), dim3(256), 0, stream, part, O);
    } else {
      hipLaunchKernelGGL(alibi_attn4, dim3(1024), dim3(256), 0, stream, Q, Kb, VT, O);
    }
  } else {
    hipLaunchKernelGGL(alibi_attn_fb, dim3(512), dim3(256), 0, stream, Q, K, V, O);
  }
}

// Round 11
// 83.029 us; speedup vs baseline: 3.2226x; 3.2226x over previous
//
#include <hip/hip_runtime.h>
#include <hip/hip_bf16.h>
#include <stdint.h>

typedef float f4    __attribute__((ext_vector_type(4)));
typedef float f32x4 __attribute__((ext_vector_type(4)));
typedef short s16x8 __attribute__((ext_vector_type(8)));
typedef short s16x4 __attribute__((ext_vector_type(4)));
typedef unsigned short u16;

#define T_LEN 4096
#define NHEAD 16
#define DHEAD 64
#define KVBLK 64
#define NT    (T_LEN / KVBLK)

#if __has_builtin(__builtin_amdgcn_exp2f)
#define EXP2(x) __builtin_amdgcn_exp2f(x)
#else
#define EXP2(x) exp2f(x)
#endif

// partial slot: 64 rows x 64 d acc + 64 lsum = 4160 floats
#define SLOT_F 4160
#define CONV_BYTES (16u * 4096u * 64u * 2u * 2u)     // Kb + VT bf16 = 16.78 MB
// slots(NCB) = 704 + 256*NCB  (h8,h9:128 each; h10:192; h11:256; h12-15: 64*NCB each)
#define CHUNK_BYTES(NCB) ((size_t)CONV_BYTES + (size_t)(704 + 256*(NCB)) * SLOT_F * 4u)

__device__ __forceinline__ uint32_t pk2(float a, float b){
  uint32_t ua = __builtin_bit_cast(uint32_t, a) + 0x8000u;
  uint32_t ub = __builtin_bit_cast(uint32_t, b) + 0x8000u;
  return __builtin_amdgcn_perm(ub, ua, 0x07060302u);
}
__device__ __forceinline__ int swk(int r){ return (r ^ (r >> 3)) & 7; }
__device__ __forceinline__ int sw(int r){ return swk(r) << 3; }
__device__ __forceinline__ int slotbase(int h, int ncb){
  return (h <= 9) ? (h - 8) * 128 : (h == 10 ? 256 : (h == 11 ? 448 : 704 + (h - 12) * 64 * ncb));
}

// ---------------- fused pre-pass: K -> bf16 ; V -> bf16 V^T ----------------
__global__ __launch_bounds__(256)
void cvt_kv(const float* __restrict__ K, const float* __restrict__ V,
            u16* __restrict__ Kb, u16* __restrict__ VT){
  __shared__ u16 tile[64][66];
  if (blockIdx.x < 2048){
    const size_t i = ((size_t)blockIdx.x * 256 + threadIdx.x) * 8;
    f4 a = *(const f4*)(K + i);
    f4 b = *(const f4*)(K + i + 4);
    union { uint32_t w[4]; s16x8 v; } u;
    u.w[0] = pk2(a[0], a[1]); u.w[1] = pk2(a[2], a[3]);
    u.w[2] = pk2(b[0], b[1]); u.w[3] = pk2(b[2], b[3]);
    *(s16x8*)(Kb + i) = u.v;
  } else {
    const int vb = blockIdx.x - 2048;
    const int h  = vb >> 6;
    const int kt = vb & 63;
    const int t  = threadIdx.x;
    const float* Vh = V + ((size_t)h * T_LEN + kt * 64) * DHEAD;

    const int r = t >> 2, c = (t & 3) * 16;
    f4 x0 = *(const f4*)(Vh + r*64 + c);
    f4 x1 = *(const f4*)(Vh + r*64 + c + 4);
    f4 x2 = *(const f4*)(Vh + r*64 + c + 8);
    f4 x3 = *(const f4*)(Vh + r*64 + c + 12);
    uint32_t* tp = (uint32_t*)&tile[r][c];
    tp[0] = pk2(x0[0],x0[1]); tp[1] = pk2(x0[2],x0[3]);
    tp[2] = pk2(x1[0],x1[1]); tp[3] = pk2(x1[2],x1[3]);
    tp[4] = pk2(x2[0],x2[1]); tp[5] = pk2(x2[2],x2[3]);
    tp[6] = pk2(x3[0],x3[1]); tp[7] = pk2(x3[2],x3[3]);
    __syncthreads();

    const int d = t >> 2, ks = (t & 3) * 16;
    u16* op = VT + ((size_t)h * DHEAD + d) * T_LEN + kt * 64 + ks;
    union { uint32_t w[4]; s16x8 v; } o0, o1;
#pragma unroll
    for (int q = 0; q < 4; ++q)
      o0.w[q] = (uint32_t)tile[ks + 2*q][d]     | ((uint32_t)tile[ks + 2*q + 1][d] << 16);
#pragma unroll
    for (int q = 0; q < 4; ++q)
      o1.w[q] = (uint32_t)tile[ks + 8 + 2*q][d] | ((uint32_t)tile[ks + 9 + 2*q][d] << 16);
    *(s16x8*)(op)     = o0.v;
    *(s16x8*)(op + 8) = o1.v;
  }
}

// ---------------- chunked attention (windowed + KV-split, partial combine) ----------------
template<int NCB>
__global__ __launch_bounds__(256, 4)   // 4 waves/EU floor: VGPR=64, NO spills (r10 lesson)
void alibi_attn5(const float* __restrict__ Qg,
                 const u16* __restrict__ Kb,
                 const u16* __restrict__ VTb,
                 float* __restrict__ Og,
                 float* __restrict__ part)
{
  __shared__ u16 kbuf[2][KVBLK * DHEAD];
  __shared__ u16 vbuf[2][DHEAD * KVBLK];

  // bid -> (h, qt, chunk c of n). Heavy heads first (better packing).
  const int bid = blockIdx.x;
  constexpr int B12 = 256 * NCB;
  int h, qt, c, n;
  if (bid < B12){                       // h 12..15, NC=NCB
    h = 12 + bid / (64 * NCB); int r = bid % (64 * NCB); qt = r / NCB; c = r % NCB; n = NCB;
  } else if (bid < B12 + 256){          // h 11, NC=4
    int r = bid - B12; h = 11; qt = r >> 2; c = r & 3; n = 4;
  } else if (bid < B12 + 448){          // h 10, NC=3
    int r = bid - B12 - 256; h = 10; qt = r / 3; c = r - qt * 3; n = 3;
  } else if (bid < B12 + 704){          // h 8..9, NC=2
    int r = bid - B12 - 448; h = 8 + (r >> 7); r &= 127; qt = r >> 1; c = r & 1; n = 2;
  } else {                              // h 0..7, NC=1
    int r = bid - B12 - 704; h = r >> 6; qt = r & 63; c = 0; n = 1;
  }

  const int tid  = threadIdx.x;
  const int wv   = tid >> 6;
  const int lane = tid & 63;
  const int lg   = lane >> 4;
  const int ln   = lane & 15;

  const int q0   = qt * 64;
  const int qrow = q0 + wv * 16 + ln;
  const float slope = exp2f(-0.5f * (float)(h + 1));
  const float cs = 0.125f * 1.44269504089f;
  const float bs = slope * 1.44269504089f;
  const size_t headoff = (size_t)h * T_LEN * DHEAD;

  // ALiBi window (keys with bs*dist > 36 are negligible), then chunk c of n
  const int Di = (int)(36.0f / bs);
  int lo = (q0 - Di) >> 6;           if (lo < 0) lo = 0;
  int hi = (q0 + 63 + Di) >> 6;      if (hi > NT - 1) hi = NT - 1;
  const int len = hi - lo + 1;
  const int start = lo + (c * len) / n;
  const int end   = lo + ((c + 1) * len) / n;   // exclusive

  // ---- Q fragments ----
  s16x8 qf0, qf1;
  {
    const float* qp = Qg + headoff + (size_t)qrow * DHEAD + lg * 8;
    f4 x = *(const f4*)qp;        f4 y = *(const f4*)(qp + 4);
    f4 z = *(const f4*)(qp + 32); f4 v = *(const f4*)(qp + 36);
    union { uint32_t w_[4]; s16x8 v_; } u0, u1;
    u0.w_[0] = pk2(x[0]*cs, x[1]*cs); u0.w_[1] = pk2(x[2]*cs, x[3]*cs);
    u0.w_[2] = pk2(y[0]*cs, y[1]*cs); u0.w_[3] = pk2(y[2]*cs, y[3]*cs);
    u1.w_[0] = pk2(z[0]*cs, z[1]*cs); u1.w_[1] = pk2(z[2]*cs, z[3]*cs);
    u1.w_[2] = pk2(v[0]*cs, v[1]*cs); u1.w_[3] = pk2(v[2]*cs, v[3]*cs);
    qf0 = u0.v_; qf1 = u1.v_;
  }

  f32x4 acc[4];
#pragma unroll
  for (int dt = 0; dt < 4; ++dt) acc[dt] = (f32x4)(0.0f);
  float lsum = 0.0f;
  const float base0 = (float)qrow - (float)(lg * 4);

  // ---- hoisted swizzled LDS read byte-offsets ----
  int koffs[4][2];
#pragma unroll
  for (int kt = 0; kt < 4; ++kt){
    const int key = kt*16 + ln, sz = sw(key);
    koffs[kt][0] = (((key*64      + lg*8) ^ sz)) * 2;
    koffs[kt][1] = (((key*64 + 32 + lg*8) ^ sz)) * 2;
  }
  int voffs[4][4];
#pragma unroll
  for (int dt = 0; dt < 4; ++dt){
    const int d = dt*16 + ln, sz = sw(d);
#pragma unroll
    for (int kt = 0; kt < 4; ++kt)
      voffs[dt][kt] = (((d*64 + kt*16 + lg*4) ^ sz)) * 2;
  }

  // ---- staging: linear LDS dest, inverse-swizzled global source ----
  const u16* Kh = Kb  + headoff;
  const u16* Vh = VTb + headoff;
  const int sA = wv * 128 + lane;
  const int sB = sA + 64;
  const int keyA = sA >> 3, gA = (sA & 7) ^ swk(keyA);
  const int keyB = sB >> 3, gB = (sB & 7) ^ swk(keyB);
  const int kidxA = keyA * 64 + gA * 8;
  const int kidxB = keyB * 64 + gB * 8;
  const int vidxA = keyA * T_LEN + gA * 8;
  const int vidxB = keyB * T_LEN + gB * 8;
  const int dstA = sA * 16, dstB = sB * 16;

  s16x8 rkA, rkB, rvA, rvB;
  auto ldregs = [&](int t){
    const u16* kp = Kh + (size_t)t * (KVBLK * DHEAD);
    const u16* vp = Vh + (size_t)t * KVBLK;
    rkA = *(const s16x8*)(kp + kidxA);  rkB = *(const s16x8*)(kp + kidxB);
    rvA = *(const s16x8*)(vp + vidxA);  rvB = *(const s16x8*)(vp + vidxB);
  };
  auto wrregs = [&](u16* kb_, u16* vb_){
    *(s16x8*)((char*)kb_ + dstA) = rkA;  *(s16x8*)((char*)kb_ + dstB) = rkB;
    *(s16x8*)((char*)vb_ + dstA) = rvA;  *(s16x8*)((char*)vb_ + dstB) = rvB;
  };

  auto compute = [&](const u16* kb_, const u16* vb_, int kv){
    f32x4 S[4];
    __builtin_amdgcn_s_setprio(1);
#pragma unroll
    for (int kt = 0; kt < 4; ++kt){
      s16x8 k0 = *(const s16x8*)((const char*)kb_ + koffs[kt][0]);
      s16x8 k1 = *(const s16x8*)((const char*)kb_ + koffs[kt][1]);
      f32x4 cc = (f32x4)(0.0f);
      cc = __builtin_amdgcn_mfma_f32_16x16x32_bf16(k0, qf0, cc, 0, 0, 0);
      cc = __builtin_amdgcn_mfma_f32_16x16x32_bf16(k1, qf1, cc, 0, 0, 0);
      S[kt] = cc;
    }
    __builtin_amdgcn_s_setprio(0);

    const float bi = base0 - (float)(kv * KVBLK);
    float p[16];
#pragma unroll
    for (int kt = 0; kt < 4; ++kt)
#pragma unroll
      for (int r = 0; r < 4; ++r)
        p[kt*4 + r] = EXP2(fmaf(-bs, fabsf(bi - (float)(kt*16 + r)), S[kt][r]));

    lsum += (((p[0]+p[1]) + (p[2]+p[3])) + ((p[4]+p[5]) + (p[6]+p[7])))
          + (((p[8]+p[9]) + (p[10]+p[11])) + ((p[12]+p[13]) + (p[14]+p[15])));

    s16x4 pb[4];
#pragma unroll
    for (int kt = 0; kt < 4; ++kt){
      union { uint32_t w_[2]; s16x4 v_; } u;
      u.w_[0] = pk2(p[kt*4+0], p[kt*4+1]);
      u.w_[1] = pk2(p[kt*4+2], p[kt*4+3]);
      pb[kt] = u.v_;
    }

    __builtin_amdgcn_s_setprio(1);
#pragma unroll
    for (int dt = 0; dt < 4; ++dt){
#pragma unroll
      for (int kt = 0; kt < 4; ++kt){
        const s16x4 vf = *(const s16x4*)((const char*)vb_ + voffs[dt][kt]);
        acc[dt] = __builtin_amdgcn_mfma_f32_16x16x16bf16_1k(vf, pb[kt], acc[dt], 0, 0, 0);
      }
    }
    __builtin_amdgcn_s_setprio(0);
  };

  if (start < end){
    ldregs(start);
    wrregs(kbuf[0], vbuf[0]);
    __syncthreads();

    const int hi_i = end - 1;
    int t = start;
#pragma unroll 1
    while (t + 1 < hi_i){
      ldregs(t + 1);
      compute(kbuf[0], vbuf[0], t);
      wrregs(kbuf[1], vbuf[1]);
      __syncthreads();
      ldregs(t + 2);
      compute(kbuf[1], vbuf[1], t + 1);
      wrregs(kbuf[0], vbuf[0]);
      __syncthreads();
      t += 2;
    }
    if (t < hi_i){
      ldregs(t + 1);
      compute(kbuf[0], vbuf[0], t);
      wrregs(kbuf[1], vbuf[1]);
      __syncthreads();
      compute(kbuf[1], vbuf[1], t + 1);
    } else {
      compute(kbuf[0], vbuf[0], t);
    }
  }

  // ---- row lsum reduce ----
  lsum += __shfl_xor(lsum, 16, 64);
  lsum += __shfl_xor(lsum, 32, 64);

  if (n == 1){
    const float inv = 1.0f / lsum;
    float* op = Og + headoff + (size_t)qrow * DHEAD + lg * 4;
#pragma unroll
    for (int dt = 0; dt < 4; ++dt){
      f4 o;
      o[0] = acc[dt][0] * inv; o[1] = acc[dt][1] * inv;
      o[2] = acc[dt][2] * inv; o[3] = acc[dt][3] * inv;
      *(f4*)(op + dt*16) = o;
    }
  } else {
    float* slot = part + (size_t)(slotbase(h, NCB) + qt * n + c) * SLOT_F;
    const int row = wv * 16 + ln;
    float* op = slot + row * 64 + lg * 4;
#pragma unroll
    for (int dt = 0; dt < 4; ++dt)
      *(f4*)(op + dt*16) = acc[dt];
    if (lg == 0) slot[4096 + row] = lsum;
  }
}

// ---------------- combine partials for h 8..15 ----------------
template<int NCB>
__global__ __launch_bounds__(256)
void combine_k(const float* __restrict__ part, float* __restrict__ Og){
  const int h  = 8 + (blockIdx.x >> 6);
  const int qt = blockIdx.x & 63;
  const int n  = (h <= 9) ? 2 : (h == 10 ? 3 : (h == 11 ? 4 : NCB));
  const int sb = slotbase(h, NCB) + qt * n;

  const int t   = threadIdx.x;
  const int row = t >> 2;
  const int seg = (t & 3) * 16;

  f4 a0 = (f4)(0.0f), a1 = (f4)(0.0f), a2 = (f4)(0.0f), a3 = (f4)(0.0f);
  float l = 0.0f;
#pragma unroll 1
  for (int c = 0; c < n; ++c){
    const float* sp = part + (size_t)(sb + c) * SLOT_F;
    const float* rp = sp + row * 64 + seg;
    a0 += *(const f4*)(rp);
    a1 += *(const f4*)(rp + 4);
    a2 += *(const f4*)(rp + 8);
    a3 += *(const f4*)(rp + 12);
    l  += sp[4096 + row];
  }
  const float inv = 1.0f / l;
  float* op = Og + (((size_t)h * T_LEN + qt * 64 + row) * DHEAD) + seg;
  f4 o0, o1, o2, o3;
  o0[0]=a0[0]*inv; o0[1]=a0[1]*inv; o0[2]=a0[2]*inv; o0[3]=a0[3]*inv;
  o1[0]=a1[0]*inv; o1[1]=a1[1]*inv; o1[2]=a1[2]*inv; o1[3]=a1[3]*inv;
  o2[0]=a2[0]*inv; o2[1]=a2[1]*inv; o2[2]=a2[2]*inv; o2[3]=a2[3]*inv;
  o3[0]=a3[0]*inv; o3[1]=a3[1]*inv; o3[2]=a3[2]*inv; o3[3]=a3[3]*inv;
  *(f4*)(op)      = o0;
  *(f4*)(op + 4)  = o1;
  *(f4*)(op + 8)  = o2;
  *(f4*)(op + 12) = o3;
}

// ---------------- windowed, unsplit kernel (ws >= 16.8MB fallback) ----------------
__global__ __launch_bounds__(256, 4)
void alibi_attn4(const float* __restrict__ Qg,
                 const u16* __restrict__ Kb,
                 const u16* __restrict__ VTb,
                 float* __restrict__ Og)
{
  __shared__ u16 kbuf[2][KVBLK * DHEAD];
  __shared__ u16 vbuf[2][DHEAD * KVBLK];

  const int bid = blockIdx.x;
  const int fid = (bid & 7) * 128 + (bid >> 3);
  const int h  = fid & 15;
  const int qt = fid >> 4;

  const int tid  = threadIdx.x;
  const int wv   = tid >> 6;
  const int lane = tid & 63;
  const int lg   = lane >> 4;
  const int ln   = lane & 15;

  const int q0   = qt * 64;
  const int qrow = q0 + wv * 16 + ln;
  const float slope = exp2f(-0.5f * (float)(h + 1));
  const float cs = 0.125f * 1.44269504089f;
  const float bs = slope * 1.44269504089f;
  const size_t headoff = (size_t)h * T_LEN * DHEAD;

  const int Di = (int)(36.0f / bs);
  int lo = (q0 - Di) >> 6;           if (lo < 0) lo = 0;
  int hi = (q0 + 63 + Di) >> 6;      if (hi > NT - 1) hi = NT - 1;

  s16x8 qf0, qf1;
  {
    const float* qp = Qg + headoff + (size_t)qrow * DHEAD + lg * 8;
    f4 x = *(const f4*)qp;        f4 y = *(const f4*)(qp + 4);
    f4 z = *(const f4*)(qp + 32); f4 v = *(const f4*)(qp + 36);
    union { uint32_t w_[4]; s16x8 v_; } u0, u1;
    u0.w_[0] = pk2(x[0]*cs, x[1]*cs); u0.w_[1] = pk2(x[2]*cs, x[3]*cs);
    u0.w_[2] = pk2(y[0]*cs, y[1]*cs); u0.w_[3] = pk2(y[2]*cs, y[3]*cs);
    u1.w_[0] = pk2(z[0]*cs, z[1]*cs); u1.w_[1] = pk2(z[2]*cs, z[3]*cs);
    u1.w_[2] = pk2(v[0]*cs, v[1]*cs); u1.w_[3] = pk2(v[2]*cs, v[3]*cs);
    qf0 = u0.v_; qf1 = u1.v_;
  }

  f32x4 acc[4];
#pragma unroll
  for (int dt = 0; dt < 4; ++dt) acc[dt] = (f32x4)(0.0f);
  float lsum = 0.0f;
  const float base0 = (float)qrow - (float)(lg * 4);

  int koffs[4][2];
#pragma unroll
  for (int kt = 0; kt < 4; ++kt){
    const int key = kt*16 + ln, sz = sw(key);
    koffs[kt][0] = (((key*64      + lg*8) ^ sz)) * 2;
    koffs[kt][1] = (((key*64 + 32 + lg*8) ^ sz)) * 2;
  }
  int voffs[4][4];
#pragma unroll
  for (int dt = 0; dt < 4; ++dt){
    const int d = dt*16 + ln, sz = sw(d);
#pragma unroll
    for (int kt = 0; kt < 4; ++kt)
      voffs[dt][kt] = (((d*64 + kt*16 + lg*4) ^ sz)) * 2;
  }

  const u16* Kh = Kb  + headoff;
  const u16* Vh = VTb + headoff;
  const int sA = wv * 128 + lane;
  const int sB = sA + 64;
  const int keyA = sA >> 3, gA = (sA & 7) ^ swk(keyA);
  const int keyB = sB >> 3, gB = (sB & 7) ^ swk(keyB);
  const int kidxA = keyA * 64 + gA * 8;
  const int kidxB = keyB * 64 + gB * 8;
  const int vidxA = keyA * T_LEN + gA * 8;
  const int vidxB = keyB * T_LEN + gB * 8;
  const int dstA = sA * 16, dstB = sB * 16;

  s16x8 rkA, rkB, rvA, rvB;
  auto ldregs = [&](int t){
    const u16* kp = Kh + (size_t)t * (KVBLK * DHEAD);
    const u16* vp = Vh + (size_t)t * KVBLK;
    rkA = *(const s16x8*)(kp + kidxA);  rkB = *(const s16x8*)(kp + kidxB);
    rvA = *(const s16x8*)(vp + vidxA);  rvB = *(const s16x8*)(vp + vidxB);
  };
  auto wrregs = [&](u16* kb_, u16* vb_){
    *(s16x8*)((char*)kb_ + dstA) = rkA;  *(s16x8*)((char*)kb_ + dstB) = rkB;
    *(s16x8*)((char*)vb_ + dstA) = rvA;  *(s16x8*)((char*)vb_ + dstB) = rvB;
  };

  auto compute = [&](const u16* kb_, const u16* vb_, int kv){
    f32x4 S[4];
    __builtin_amdgcn_s_setprio(1);
#pragma unroll
    for (int kt = 0; kt < 4; ++kt){
      s16x8 k0 = *(const s16x8*)((const char*)kb_ + koffs[kt][0]);
      s16x8 k1 = *(const s16x8*)((const char*)kb_ + koffs[kt][1]);
      f32x4 cc = (f32x4)(0.0f);
      cc = __builtin_amdgcn_mfma_f32_16x16x32_bf16(k0, qf0, cc, 0, 0, 0);
      cc = __builtin_amdgcn_mfma_f32_16x16x32_bf16(k1, qf1, cc, 0, 0, 0);
      S[kt] = cc;
    }
    __builtin_amdgcn_s_setprio(0);

    const float bi = base0 - (float)(kv * KVBLK);
    float p[16];
#pragma unroll
    for (int kt = 0; kt < 4; ++kt)
#pragma unroll
      for (int r = 0; r < 4; ++r)
        p[kt*4 + r] = EXP2(fmaf(-bs, fabsf(bi - (float)(kt*16 + r)), S[kt][r]));

    lsum += (((p[0]+p[1]) + (p[2]+p[3])) + ((p[4]+p[5]) + (p[6]+p[7])))
          + (((p[8]+p[9]) + (p[10]+p[11])) + ((p[12]+p[13]) + (p[14]+p[15])));

    s16x4 pb[4];
#pragma unroll
    for (int kt = 0; kt < 4; ++kt){
      union { uint32_t w_[2]; s16x4 v_; } u;
      u.w_[0] = pk2(p[kt*4+0], p[kt*4+1]);
      u.w_[1] = pk2(p[kt*4+2], p[kt*4+3]);
      pb[kt] = u.v_;
    }

    __builtin_amdgcn_s_setprio(1);
#pragma unroll
    for (int dt = 0; dt < 4; ++dt){
#pragma unroll
      for (int kt = 0; kt < 4; ++kt){
        const s16x4 vf = *(const s16x4*)((const char*)vb_ + voffs[dt][kt]);
        acc[dt] = __builtin_amdgcn_mfma_f32_16x16x16bf16_1k(vf, pb[kt], acc[dt], 0, 0, 0);
      }
    }
    __builtin_amdgcn_s_setprio(0);
  };

  ldregs(lo);
  wrregs(kbuf[0], vbuf[0]);
  __syncthreads();

  int t = lo;
#pragma unroll 1
  while (t + 1 < hi){
    ldregs(t + 1);
    compute(kbuf[0], vbuf[0], t);
    wrregs(kbuf[1], vbuf[1]);
    __syncthreads();
    ldregs(t + 2);
    compute(kbuf[1], vbuf[1], t + 1);
    wrregs(kbuf[0], vbuf[0]);
    __syncthreads();
    t += 2;
  }
  if (t < hi){
    ldregs(t + 1);
    compute(kbuf[0], vbuf[0], t);
    wrregs(kbuf[1], vbuf[1]);
    __syncthreads();
    compute(kbuf[1], vbuf[1], t + 1);
  } else {
    compute(kbuf[0], vbuf[0], t);
  }

  lsum += __shfl_xor(lsum, 16, 64);
  lsum += __shfl_xor(lsum, 32, 64);
  const float inv = 1.0f / lsum;
  float* op = Og + headoff + (size_t)qrow * DHEAD + lg * 4;
#pragma unroll
  for (int dt = 0; dt < 4; ++dt){
    f4 o;
    o[0] = acc[dt][0] * inv; o[1] = acc[dt][1] * inv;
    o[2] = acc[dt][2] * inv; o[3] = acc[dt][3] * inv;
    *(f4*)(op + dt*16) = o;
  }
}

// ---------------- no-ws fallback (round-5 kernel) ----------------
__global__ __launch_bounds__(256, 2)
void alibi_attn_fb(const float* __restrict__ Qg,
                   const float* __restrict__ Kg,
                   const float* __restrict__ Vg,
                   float* __restrict__ Og)
{
  __shared__ u16 kbuf[2][KVBLK * DHEAD];
  __shared__ u16 vbuf[2][DHEAD * KVBLK];

  const int bid = blockIdx.x;
  const int fid = (bid & 7) * 64 + (bid >> 3);
  const int h  = fid >> 5;
  const int qt = fid & 31;

  const int tid  = threadIdx.x;
  const int wave = tid >> 6;
  const int lane = tid & 63;
  const int lg   = lane >> 4;
  const int ln   = lane & 15;

  const int qb = qt * 128 + wave * 32;
  const float slope = exp2f(-0.5f * (float)(h + 1));
  const float cs = 0.125f * 1.44269504089f;
  const float bs = slope * 1.44269504089f;
  const size_t headoff = (size_t)h * T_LEN * DHEAD;

  s16x8 qf[2][2];
#pragma unroll
  for (int rg = 0; rg < 2; ++rg)
#pragma unroll
    for (int dh = 0; dh < 2; ++dh){
      const float* qp = Qg + headoff + (size_t)(qb + rg*16 + ln) * DHEAD + dh*32 + lg*8;
      f4 x = *(const f4*)qp;
      f4 y = *(const f4*)(qp + 4);
      union { uint32_t w[4]; s16x8 v; } u;
      u.w[0] = pk2(x[0]*cs, x[1]*cs);
      u.w[1] = pk2(x[2]*cs, x[3]*cs);
      u.w[2] = pk2(y[0]*cs, y[1]*cs);
      u.w[3] = pk2(y[2]*cs, y[3]*cs);
      qf[rg][dh] = u.v;
    }

  f32x4 acc[2][4];
#pragma unroll
  for (int rg = 0; rg < 2; ++rg)
#pragma unroll
    for (int dt = 0; dt < 4; ++dt) acc[rg][dt] = (f32x4)(0.0f);
  float mreg[2] = {-1e30f, -1e30f};
  float lreg[2] = {0.0f, 0.0f};
  const float qposf[2] = {(float)(qb + ln), (float)(qb + 16 + ln)};
  const float koffb = (float)(lg * 4);

  f4 st4[8];
  const int vk0  = (tid >> 2) * 2;
  const int vseg = (tid & 3) * 16;
  const int krow = (tid - 128) >> 1;
  const int kseg = ((tid - 128) & 1) * 32;
  const float* Vb = Vg + headoff;
  const float* Kb_ = Kg + headoff;

  auto stage_load = [&](int kv){
    const int kb = kv * KVBLK;
    if (tid < 128){
      const float* vp = Vb + (size_t)(kb + vk0) * DHEAD + vseg;
      st4[0] = *(const f4*)(vp);      st4[1] = *(const f4*)(vp + 4);
      st4[2] = *(const f4*)(vp + 8);  st4[3] = *(const f4*)(vp + 12);
      st4[4] = *(const f4*)(vp + 64); st4[5] = *(const f4*)(vp + 68);
      st4[6] = *(const f4*)(vp + 72); st4[7] = *(const f4*)(vp + 76);
    } else {
      const float* kp = Kb_ + (size_t)(kb + krow) * DHEAD + kseg;
#pragma unroll
      for (int j = 0; j < 8; ++j) st4[j] = *(const f4*)(kp + j*4);
    }
  };
  auto stage_store = [&](int b){
    if (tid < 128){
#pragma unroll
      for (int i = 0; i < 16; ++i){
        const int d = vseg + i;
        uint32_t pr = pk2(st4[i>>2][i&3], st4[4 + (i>>2)][i&3]);
        *(uint32_t*)&vbuf[b][(d*64 + vk0) ^ sw(d)] = pr;
      }
    } else {
#pragma unroll
      for (int i = 0; i < 4; ++i){
        union { uint32_t w[4]; s16x8 v; } u;
        u.w[0] = pk2(st4[i*2][0],   st4[i*2][1]);
        u.w[1] = pk2(st4[i*2][2],   st4[i*2][3]);
        u.w[2] = pk2(st4[i*2+1][0], st4[i*2+1][1]);
        u.w[3] = pk2(st4[i*2+1][2], st4[i*2+1][3]);
        *(s16x8*)&kbuf[b][(krow*64 + kseg + i*8) ^ sw(krow)] = u.v;
      }
    }
  };

  stage_load(0);
  stage_store(0);
  __syncthreads();
  int cur = 0;

#pragma unroll 1
  for (int kv = 0; kv < NT; ++kv){
    if (kv + 1 < NT) stage_load(kv + 1);

    const float kbf = (float)(kv * KVBLK);
    const u16* kb_ = kbuf[cur];
    const u16* vb_ = vbuf[cur];

    s16x8 kf[4][2];
#pragma unroll
    for (int kt = 0; kt < 4; ++kt){
      const int key = kt*16 + ln;
      const int sz  = sw(key);
      kf[kt][0] = *(const s16x8*)&kb_[(key*64 +      lg*8) ^ sz];
      kf[kt][1] = *(const s16x8*)&kb_[(key*64 + 32 + lg*8) ^ sz];
    }
    f32x4 S[2][4];
#pragma unroll
    for (int rg = 0; rg < 2; ++rg)
#pragma unroll
      for (int kt = 0; kt < 4; ++kt){
        f32x4 c = (f32x4)(0.0f);
        c = __builtin_amdgcn_mfma_f32_16x16x32_bf16(kf[kt][0], qf[rg][0], c, 0, 0, 0);
        c = __builtin_amdgcn_mfma_f32_16x16x32_bf16(kf[kt][1], qf[rg][1], c, 0, 0, 0);
        S[rg][kt] = c;
      }

    s16x4 pb[2][4];
#pragma unroll
    for (int rg = 0; rg < 2; ++rg){
      const float base = qposf[rg] - kbf - koffb;
#pragma unroll
      for (int kt = 0; kt < 4; ++kt)
#pragma unroll
        for (int r = 0; r < 4; ++r)
          S[rg][kt][r] = fmaf(-bs, fabsf(base - (float)(kt*16 + r)), S[rg][kt][r]);

      float a0 = fmaxf(fmaxf(S[rg][0][0], S[rg][0][1]), fmaxf(S[rg][0][2], S[rg][0][3]));
      float a1 = fmaxf(fmaxf(S[rg][1][0], S[rg][1][1]), fmaxf(S[rg][1][2], S[rg][1][3]));
      float a2 = fmaxf(fmaxf(S[rg][2][0], S[rg][2][1]), fmaxf(S[rg][2][2], S[rg][2][3]));
      float a3 = fmaxf(fmaxf(S[rg][3][0], S[rg][3][1]), fmaxf(S[rg][3][2], S[rg][3][3]));
      float mx = fmaxf(fmaxf(a0, a1), fmaxf(a2, a3));
      mx = fmaxf(mx, __shfl_xor(mx, 16, 64));
      mx = fmaxf(mx, __shfl_xor(mx, 32, 64));

      const float mo = mreg[rg];
      const float mn = fmaxf(mo, mx);
      const float scl = EXP2(mo - mn);
      mreg[rg] = mn;

      float p[16];
#pragma unroll
      for (int kt = 0; kt < 4; ++kt)
#pragma unroll
        for (int r = 0; r < 4; ++r)
          p[kt*4 + r] = EXP2(S[rg][kt][r] - mn);

      float s0 = (p[0]+p[1]) + (p[2]+p[3]);
      float s1 = (p[4]+p[5]) + (p[6]+p[7]);
      float s2 = (p[8]+p[9]) + (p[10]+p[11]);
      float s3 = (p[12]+p[13]) + (p[14]+p[15]);
      float sum = (s0+s1) + (s2+s3);
      sum += __shfl_xor(sum, 16, 64);
      sum += __shfl_xor(sum, 32, 64);
      lreg[rg] = lreg[rg] * scl + sum;

#pragma unroll
      for (int dt = 0; dt < 4; ++dt) acc[rg][dt] *= scl;

#pragma unroll
      for (int kt = 0; kt < 4; ++kt){
        union { uint32_t w[2]; s16x4 v; } u;
        u.w[0] = pk2(p[kt*4+0], p[kt*4+1]);
        u.w[1] = pk2(p[kt*4+2], p[kt*4+3]);
        pb[rg][kt] = u.v;
      }
    }

#pragma unroll
    for (int dt = 0; dt < 4; ++dt){
      const int d  = dt*16 + ln;
      const int sz = sw(d);
#pragma unroll
      for (int kt = 0; kt < 4; ++kt){
        const s16x4 vf = *(const s16x4*)&vb_[(d*64 + kt*16 + lg*4) ^ sz];
        acc[0][dt] = __builtin_amdgcn_mfma_f32_16x16x16bf16_1k(vf, pb[0][kt], acc[0][dt], 0, 0, 0);
        acc[1][dt] = __builtin_amdgcn_mfma_f32_16x16x16bf16_1k(vf, pb[1][kt], acc[1][dt], 0, 0, 0);
      }
    }

    if (kv + 1 < NT){
      stage_store(cur ^ 1);
      __syncthreads();
      cur ^= 1;
    }
  }

#pragma unroll
  for (int rg = 0; rg < 2; ++rg){
    const float inv = 1.0f / lreg[rg];
    float* op = Og + headoff + (size_t)(qb + rg*16 + ln) * DHEAD + lg*4;
#pragma unroll
    for (int dt = 0; dt < 4; ++dt){
      f4 o;
      o[0] = acc[rg][dt][0] * inv;
      o[1] = acc[rg][dt][1] * inv;
      o[2] = acc[rg][dt][2] * inv;
      o[3] = acc[rg][dt][3] * inv;
      *(f4*)(op + dt*16) = o;
    }
  }
}

extern "C" void kernel_launch(void* const* d_in, const int* in_sizes, int n_in,
                              void* d_out, int out_size, void* d_ws, size_t ws_size,
                              hipStream_t stream)
{
  const float* Q = (const float*)d_in[0];
  const float* K = (const float*)d_in[1];
  const float* V = (const float*)d_in[2];
  float* O = (float*)d_out;

  if (ws_size >= CONV_BYTES){
    u16* Kb = (u16*)d_ws;
    u16* VT = Kb + (size_t)NHEAD * T_LEN * DHEAD;
    hipLaunchKernelGGL(cvt_kv, dim3(3072), dim3(256), 0, stream, K, V, Kb, VT);

    if (ws_size >= CHUNK_BYTES(5)){
      float* part = (float*)((char*)d_ws + CONV_BYTES);
      hipLaunchKernelGGL((alibi_attn5<5>), dim3(1216 + 256*5), dim3(256), 0, stream, Q, Kb, VT, O, part);
      hipLaunchKernelGGL((combine_k<5>), dim3(512), dim3(256), 0, stream, part, O);
    } else if (ws_size >= CHUNK_BYTES(4)){
      float* part = (float*)((char*)d_ws + CONV_BYTES);
      hipLaunchKernelGGL((alibi_attn5<4>), dim3(1216 + 256*4), dim3(256), 0, stream, Q, Kb, VT, O, part);
      hipLaunchKernelGGL((combine_k<4>), dim3(512), dim3(256), 0, stream, part, O);
    } else {
      hipLaunchKernelGGL(alibi_attn4, dim3(1024), dim3(256), 0, stream, Q, Kb, VT, O);
    }
  } else {
    hipLaunchKernelGGL(alibi_attn_fb, dim3(512), dim3(256), 0, stream, Q, K, V, O);
  }
}